// Round 1
// baseline (1724.816 us; speedup 1.0000x reference)
//
#include <hip/hip_runtime.h>

#define NN 16384
#define DIN 512
#define DOUT 128

typedef __bf16 bf16x8 __attribute__((ext_vector_type(8)));
typedef float floatx4 __attribute__((ext_vector_type(4)));

__device__ __forceinline__ unsigned short f2bf(float f) {
    unsigned u = __builtin_bit_cast(unsigned, f);
    u += 0x7FFFu + ((u >> 16) & 1u);   // RNE
    return (unsigned short)(u >> 16);
}

// ---------------------------------------------------------------------------
// Kernel 1: xT[d][n] = sum_c inputs[n][c] * W[c][d], output bf16 (transposed
// so kernel 2's B-fragment LDS loads are contiguous ds_read_b128).
// Block = 256 threads, tile = 32 n-rows x 128 d-cols, c-chunks of 64.
// Grid = 16384/32 = 512 blocks (2 per CU).
// ---------------------------------------------------------------------------
__global__ __launch_bounds__(256) void xw_kernel(
        const float* __restrict__ inp, const float* __restrict__ w,
        unsigned short* __restrict__ xT) {
    __shared__ float sIn[32][68];   // pad 68: 272B rows, float4-aligned, 2-way banks (free)
    __shared__ float sW[64][128];
    const int tid = threadIdx.x;
    const int n0 = blockIdx.x * 32;
    const int tn = tid >> 4;   // 0..15 -> n pair
    const int td = tid & 15;   // 0..15 -> 8 d's

    float acc[2][8];
#pragma unroll
    for (int i = 0; i < 2; ++i)
#pragma unroll
        for (int j = 0; j < 8; ++j) acc[i][j] = 0.f;

    for (int c0 = 0; c0 < DIN; c0 += 64) {
        __syncthreads();
        // stage inputs tile: 32x64 f32 = 512 float4 slots, 2 per thread
#pragma unroll
        for (int p = 0; p < 2; ++p) {
            int s = tid + p * 256;
            int row = s >> 4, c4 = (s & 15) << 2;
            *(float4*)&sIn[row][c4] =
                *(const float4*)&inp[(size_t)(n0 + row) * DIN + c0 + c4];
        }
        // stage weights tile: 64x128 f32 = 2048 float4 slots, 8 per thread
#pragma unroll
        for (int p = 0; p < 8; ++p) {
            int s = tid + p * 256;
            int row = s >> 5, c4 = (s & 31) << 2;
            *(float4*)&sW[row][c4] =
                *(const float4*)&w[(size_t)(c0 + row) * DOUT + c4];
        }
        __syncthreads();
#pragma unroll 8
        for (int cc = 0; cc < 64; ++cc) {
            float a0 = sIn[tn * 2 + 0][cc];
            float a1 = sIn[tn * 2 + 1][cc];
            float4 b0 = *(const float4*)&sW[cc][td * 8];
            float4 b1 = *(const float4*)&sW[cc][td * 8 + 4];
            float bb[8] = {b0.x, b0.y, b0.z, b0.w, b1.x, b1.y, b1.z, b1.w};
#pragma unroll
            for (int j = 0; j < 8; ++j) {
                acc[0][j] += a0 * bb[j];
                acc[1][j] += a1 * bb[j];
            }
        }
    }
#pragma unroll
    for (int i = 0; i < 2; ++i)
#pragma unroll
        for (int j = 0; j < 8; ++j) {
            int d = td * 8 + j;
            xT[(size_t)d * NN + n0 + tn * 2 + i] = f2bf(acc[i][j]);
        }
}

// ---------------------------------------------------------------------------
// Kernel 2: out[m][d] = sum_k adj[m][k] * x[k][d], bf16 MFMA, fp32 accum.
// BM=64, BN=128(=DOUT), BK=64. 512 threads = 8 waves; wave w: row-tile rt=w&3
// (16 rows), col-group cg=w>>2 (4 x 16-col tiles). mfma_f32_16x16x32_bf16.
// adj fp32 -> bf16 converted during staging. Register-prefetch pipeline.
// Grid = 16384/64 = 256 blocks (1/CU). Memory-bound on the 1.07 GB adj read.
// ---------------------------------------------------------------------------
__global__ __launch_bounds__(512, 2) void adj_gemm(
        const float* __restrict__ adj, const unsigned short* __restrict__ xT,
        float* __restrict__ out) {
    // pad +8 bf16: 144 B rows = 16B-aligned, 2-way bank aliasing only (free)
    __shared__ unsigned short As[64][72];    // adj tile, bf16
    __shared__ unsigned short Bs[128][72];   // xT tile, bf16 ([n][k] layout)
    const int tid  = threadIdx.x;
    const int m0   = blockIdx.x * 64;
    const int w    = tid >> 6;
    const int lane = tid & 63;
    const int rt   = w & 3;       // row tile 0..3
    const int cg   = w >> 2;      // col group 0..1
    const int lm   = lane & 15;
    const int quad = lane >> 4;

    // staging slot geometry (2 slots per thread each)
    const int arow = tid >> 4;           // + p*32
    const int ac4  = (tid & 15) << 2;
    const int brow = tid >> 3;           // + p*64
    const int bc8  = (tid & 7) << 3;

    const floatx4 zero = {0.f, 0.f, 0.f, 0.f};
    floatx4 acc[4] = {zero, zero, zero, zero};

    float4 ra[2];
    uint4  rb[2];
    // prologue: load tile kt=0 into registers
#pragma unroll
    for (int p = 0; p < 2; ++p)
        ra[p] = *(const float4*)&adj[(size_t)(m0 + arow + p * 32) * NN + ac4];
#pragma unroll
    for (int p = 0; p < 2; ++p)
        rb[p] = *(const uint4*)&xT[(size_t)(brow + p * 64) * NN + bc8];

    for (int kt = 0; kt < NN / 64; ++kt) {
        __syncthreads();   // previous iter's readers done
        // registers -> LDS (adj converted to bf16)
#pragma unroll
        for (int p = 0; p < 2; ++p) {
            ushort4 h;
            h.x = f2bf(ra[p].x); h.y = f2bf(ra[p].y);
            h.z = f2bf(ra[p].z); h.w = f2bf(ra[p].w);
            *(ushort4*)&As[arow + p * 32][ac4] = h;
        }
#pragma unroll
        for (int p = 0; p < 2; ++p)
            *(uint4*)&Bs[brow + p * 64][bc8] = rb[p];
        __syncthreads();
        // prefetch next tile (overlaps the MFMA phase below)
        if (kt + 1 < NN / 64) {
            const int k0 = (kt + 1) * 64;
#pragma unroll
            for (int p = 0; p < 2; ++p)
                ra[p] = *(const float4*)&adj[(size_t)(m0 + arow + p * 32) * NN + k0 + ac4];
#pragma unroll
            for (int p = 0; p < 2; ++p)
                rb[p] = *(const uint4*)&xT[(size_t)(brow + p * 64) * NN + k0 + bc8];
        }
        // compute: 2 k-steps of 32, 4 col tiles per wave
#pragma unroll
        for (int kk = 0; kk < 2; ++kk) {
            bf16x8 a = *(const bf16x8*)&As[rt * 16 + lm][kk * 32 + quad * 8];
#pragma unroll
            for (int t = 0; t < 4; ++t) {
                bf16x8 b = *(const bf16x8*)&Bs[cg * 64 + t * 16 + lm][kk * 32 + quad * 8];
                acc[t] = __builtin_amdgcn_mfma_f32_16x16x32_bf16(a, b, acc[t], 0, 0, 0);
            }
        }
    }
    // epilogue: C[row = quad*4+r][col = lm] per 16x16 tile, fp32 out
#pragma unroll
    for (int t = 0; t < 4; ++t)
#pragma unroll
        for (int r = 0; r < 4; ++r)
            out[(size_t)(m0 + rt * 16 + quad * 4 + r) * DOUT + cg * 64 + t * 16 + lm] =
                acc[t][r];
}

extern "C" void kernel_launch(void* const* d_in, const int* in_sizes, int n_in,
                              void* d_out, int out_size, void* d_ws, size_t ws_size,
                              hipStream_t stream) {
    const float* inputs  = (const float*)d_in[0];   // [16384][512]
    const float* adj     = (const float*)d_in[1];   // [16384][16384]
    const float* weights = (const float*)d_in[2];   // [512][128]
    float* out = (float*)d_out;                     // [16384][128]
    unsigned short* xT = (unsigned short*)d_ws;     // [128][16384] bf16, 4 MB

    xw_kernel<<<NN / 32, 256, 0, stream>>>(inputs, weights, xT);
    adj_gemm<<<NN / 64, 512, 0, stream>>>(adj, xT, out);
}